// Round 1
// baseline (622.857 us; speedup 1.0000x reference)
//
#include <hip/hip_runtime.h>

#define NEG 0.2f

// ---------------- CSR build ----------------

__global__ void k_count(const int* __restrict__ dst, int E, int* __restrict__ deg) {
    int i = blockIdx.x * blockDim.x + threadIdx.x;
    int stride = gridDim.x * blockDim.x;
    for (; i < E; i += stride) atomicAdd(&deg[dst[i]], 1);
}

__global__ void k_scan(const int* __restrict__ deg, int* __restrict__ rowptr, int n) {
    __shared__ int sums[1024];
    int carry = 0;
    if (threadIdx.x == 0) rowptr[0] = 0;
    for (int base = 0; base < n; base += 16384) {
        int start = base + (int)threadIdx.x * 16;
        int vals[16];
        int lsum = 0;
#pragma unroll
        for (int j = 0; j < 16; j++) {
            int idx = start + j;
            vals[j] = (idx < n) ? deg[idx] : 0;
            lsum += vals[j];
        }
        sums[threadIdx.x] = lsum;
        __syncthreads();
        for (int off = 1; off < 1024; off <<= 1) {
            int t = (threadIdx.x >= (unsigned)off) ? sums[threadIdx.x - off] : 0;
            __syncthreads();
            sums[threadIdx.x] += t;
            __syncthreads();
        }
        int excl = (threadIdx.x == 0) ? 0 : sums[threadIdx.x - 1];
        int run = carry + excl;
#pragma unroll
        for (int j = 0; j < 16; j++) {
            int idx = start + j;
            if (idx < n) {
                run += vals[j];
                rowptr[idx + 1] = run;
            }
        }
        carry += sums[1023];
        __syncthreads();
    }
}

__global__ void k_scatter(const int* __restrict__ src, const int* __restrict__ dst, int E,
                          const int* __restrict__ rowptr, int* __restrict__ cursor,
                          int* __restrict__ csr_src) {
    int i = blockIdx.x * blockDim.x + threadIdx.x;
    int stride = gridDim.x * blockDim.x;
    for (; i < E; i += stride) {
        int d = dst[i];
        int slot = rowptr[d] + atomicAdd(&cursor[d], 1);
        csr_src[slot] = src[i];
    }
}

// ---------------- GEMM: Y[n,M] = X[n,K] @ W[K,M] ----------------
// 256 threads, 32 rows/block. W staged in K-halves (LDS <= 48.5KB -> 3 blocks/CU).
// Thread (r=tid>>3, cg=tid&7) computes cols {cg*4 + j*32 .. +3}, float4 LDS reads
// (lane addresses stride 4 floats -> conflict-free). Xs padded +4 to break the
// 8-way stride-K bank conflict.

template <int K, int M>
__global__ __launch_bounds__(256) void k_gemm(const float* __restrict__ X,
                                              const float* __restrict__ W,
                                              float* __restrict__ Y, int n) {
    constexpr int KH = 64;
    __shared__ float Ws[KH * M];
    __shared__ float Xs[32][K + 4];
    int tid = threadIdx.x;
    int row0 = blockIdx.x * 32;

    // stage X tile (vectorized)
    for (int idx = tid; idx < 32 * (K / 4); idx += 256) {
        int r = idx / (K / 4), c4 = idx % (K / 4);
        int gr = row0 + r;
        float4 v = make_float4(0.f, 0.f, 0.f, 0.f);
        if (gr < n) v = *reinterpret_cast<const float4*>(&X[(size_t)gr * K + c4 * 4]);
        *reinterpret_cast<float4*>(&Xs[r][c4 * 4]) = v;
    }

    constexpr int NJ = M / 32;
    float4 acc[NJ];
#pragma unroll
    for (int j = 0; j < NJ; j++) acc[j] = make_float4(0.f, 0.f, 0.f, 0.f);
    int r = tid >> 3, cg = tid & 7;

    for (int kh = 0; kh < K; kh += KH) {
        __syncthreads();
        for (int idx = tid; idx < (KH * M) / 4; idx += 256) {
            *reinterpret_cast<float4*>(&Ws[idx * 4]) =
                *reinterpret_cast<const float4*>(&W[(size_t)kh * M + idx * 4]);
        }
        __syncthreads();
        for (int k = 0; k < KH; k++) {
            float xv = Xs[r][kh + k];
#pragma unroll
            for (int j = 0; j < NJ; j++) {
                float4 wv = *reinterpret_cast<const float4*>(&Ws[k * M + cg * 4 + j * 32]);
                acc[j].x += xv * wv.x;
                acc[j].y += xv * wv.y;
                acc[j].z += xv * wv.z;
                acc[j].w += xv * wv.w;
            }
        }
    }

    int gr = row0 + r;
    if (gr < n) {
#pragma unroll
        for (int j = 0; j < NJ; j++)
            *reinterpret_cast<float4*>(&Y[(size_t)gr * M + cg * 4 + j * 32]) = acc[j];
    }
}

// ---------------- attention scalar scores: asrc/adst [n,H] ----------------

template <int H>
__global__ void k_scores(const float* __restrict__ h, const float* __restrict__ a_src,
                         const float* __restrict__ a_dst, float* __restrict__ asrc,
                         float* __restrict__ adst, int n) {
    int wid = blockIdx.x * (blockDim.x >> 6) + (threadIdx.x >> 6);
    int lane = threadIdx.x & 63;
    if (wid >= n) return;
#pragma unroll
    for (int head = 0; head < H; head++) {
        float v = h[(size_t)wid * (H * 64) + head * 64 + lane];
        float s = v * a_src[head * 64 + lane];
        float d = v * a_dst[head * 64 + lane];
#pragma unroll
        for (int m = 1; m < 64; m <<= 1) {
            s += __shfl_xor(s, m, 64);
            d += __shfl_xor(d, m, 64);
        }
        if (lane == 0) {
            asrc[wid * H + head] = s;
            adst[wid * H + head] = d;
        }
    }
}

// ---------------- GAT gather: one wave per (node, head), lane = channel ----------------
// softmax max-subtraction skipped: scores are O(1), exp can't overflow; softmax is
// shift-invariant so result matches the reference up to rounding.

template <int H>
__global__ __launch_bounds__(256) void k_gat(const float* __restrict__ h,
                                             const float* __restrict__ asrc,
                                             const float* __restrict__ adst,
                                             const int* __restrict__ rowptr,
                                             const int* __restrict__ csr_src,
                                             const float* __restrict__ bias,
                                             float* __restrict__ out, int n) {
    int wid = blockIdx.x * (blockDim.x >> 6) + (threadIdx.x >> 6);
    int lane = threadIdx.x & 63;
    int node = wid / H, head = wid % H;
    if (node >= n) return;

    int beg = rowptr[node], end = rowptr[node + 1];
    float adst_n = adst[node * H + head];
    float asrc_n = asrc[node * H + head];

    float e0 = asrc_n + adst_n;
    e0 = e0 > 0.f ? e0 : NEG * e0;
    float p_self = expf(e0);

    // phase 1: denom (lane-parallel over incident edges)
    float psum = 0.f;
    for (int i = beg + lane; i < end; i += 64) {
        int s = csr_src[i];
        float e = asrc[s * H + head] + adst_n;
        e = e > 0.f ? e : NEG * e;
        psum += expf(e);
    }
#pragma unroll
    for (int m = 1; m < 64; m <<= 1) psum += __shfl_xor(psum, m, 64);
    float inv = 1.f / (psum + p_self + 1e-16f);

    // phase 2: p-weighted aggregation, lane = channel
    float acc = p_self * h[(size_t)node * (H * 64) + head * 64 + lane];
    for (int base = beg; base < end; base += 64) {
        int cnt = min(64, end - base);
        int i = base + lane;
        float p = 0.f;
        int s = 0;
        if (i < end) {
            s = csr_src[i];
            float e = asrc[s * H + head] + adst_n;
            e = e > 0.f ? e : NEG * e;
            p = expf(e);
        }
        for (int j = 0; j < cnt; j++) {
            float pj = __shfl(p, j, 64);
            int sj = __shfl(s, j, 64);
            acc += pj * h[(size_t)sj * (H * 64) + head * 64 + lane];
        }
    }
    acc = acc * inv + bias[head * 64 + lane];
    acc = fmaxf(acc, 0.f);  // both GAT layers are followed by ReLU
    out[(size_t)node * (H * 64) + head * 64 + lane] = acc;
}

// ---------------- final linear: out[n,16] = h[n,64] @ Wl[64,16] + bl ----------------

__global__ void k_final(const float* __restrict__ h, const float* __restrict__ Wl,
                        const float* __restrict__ bl, float* __restrict__ out, int n) {
    __shared__ float Ws[64 * 16];
    __shared__ float bs[16];
    int tid = threadIdx.x;
    for (int idx = tid; idx < 64 * 16; idx += 256) Ws[idx] = Wl[idx];
    if (tid < 16) bs[tid] = bl[tid];
    __syncthreads();
    int row = blockIdx.x * 16 + (tid >> 4);
    int col = tid & 15;
    if (row >= n) return;
    const float* hr = h + (size_t)row * 64;
    float a = 0.f;
#pragma unroll
    for (int k = 0; k < 64; k++) a += hr[k] * Ws[k * 16 + col];
    out[(size_t)row * 16 + col] = a + bs[col];
}

// ---------------- launch ----------------

extern "C" void kernel_launch(void* const* d_in, const int* in_sizes, int n_in,
                              void* d_out, int out_size, void* d_ws, size_t ws_size,
                              hipStream_t stream) {
    const float* x      = (const float*)d_in[0];
    const int*   ei     = (const int*)d_in[1];
    const float* W1     = (const float*)d_in[2];
    const float* a_src1 = (const float*)d_in[3];
    const float* a_dst1 = (const float*)d_in[4];
    const float* b1     = (const float*)d_in[5];
    const float* W2     = (const float*)d_in[6];
    const float* a_src2 = (const float*)d_in[7];
    const float* a_dst2 = (const float*)d_in[8];
    const float* b2     = (const float*)d_in[9];
    const float* Wl     = (const float*)d_in[10];
    const float* bl     = (const float*)d_in[11];
    float* out = (float*)d_out;

    int n = in_sizes[0] / 128;
    int E = in_sizes[1] / 2;
    const int* src = ei;
    const int* dst = ei + E;

    char* w = (char*)d_ws;
    size_t off = 0;
    auto alloc = [&](size_t bytes) {
        void* p = w + off;
        off = (off + bytes + 255) & ~(size_t)255;
        return p;
    };
    int*   deg    = (int*)alloc((size_t)n * 4);
    int*   cursor = (int*)alloc((size_t)n * 4);
    int*   rowptr = (int*)alloc((size_t)(n + 1) * 4);
    int*   csr    = (int*)alloc((size_t)E * 4);
    float* h1     = (float*)alloc((size_t)n * 128 * 4);
    float* as1    = (float*)alloc((size_t)n * 2 * 4);
    float* ad1    = (float*)alloc((size_t)n * 2 * 4);
    float* hm     = (float*)alloc((size_t)n * 128 * 4);
    float* h2     = (float*)alloc((size_t)n * 64 * 4);
    float* as2    = (float*)alloc((size_t)n * 4);
    float* ad2    = (float*)alloc((size_t)n * 4);
    float* h3     = (float*)alloc((size_t)n * 64 * 4);

    hipMemsetAsync(deg, 0, (size_t)n * 4, stream);
    hipMemsetAsync(cursor, 0, (size_t)n * 4, stream);

    // CSR (dst-ordered), shared by both layers; self-loops handled analytically
    k_count<<<2048, 256, 0, stream>>>(dst, E, deg);
    k_scan<<<1, 1024, 0, stream>>>(deg, rowptr, n);
    k_scatter<<<2048, 256, 0, stream>>>(src, dst, E, rowptr, cursor, csr);

    // layer 1 (heads=2)
    k_gemm<128, 128><<<(n + 31) / 32, 256, 0, stream>>>(x, W1, h1, n);
    k_scores<2><<<(n + 3) / 4, 256, 0, stream>>>(h1, a_src1, a_dst1, as1, ad1, n);
    k_gat<2><<<(2 * n + 3) / 4, 256, 0, stream>>>(h1, as1, ad1, rowptr, csr, b1, hm, n);

    // layer 2 (heads=1)
    k_gemm<128, 64><<<(n + 31) / 32, 256, 0, stream>>>(hm, W2, h2, n);
    k_scores<1><<<(n + 3) / 4, 256, 0, stream>>>(h2, a_src2, a_dst2, as2, ad2, n);
    k_gat<1><<<(n + 3) / 4, 256, 0, stream>>>(h2, as2, ad2, rowptr, csr, b2, h3, n);

    // head
    k_final<<<(n + 15) / 16, 256, 0, stream>>>(h3, Wl, bl, out, n);
}

// Round 2
// 479.180 us; speedup vs baseline: 1.2998x; 1.2998x over previous
//
#include <hip/hip_runtime.h>

#define NEG 0.2f

// ---------------- CSR build ----------------

__global__ void k_count(const int* __restrict__ dst, int E, int* __restrict__ deg) {
    int i = blockIdx.x * blockDim.x + threadIdx.x;
    int stride = gridDim.x * blockDim.x;
    for (; i < E; i += stride) atomicAdd(&deg[dst[i]], 1);
}

__global__ void k_scan(const int* __restrict__ deg, int* __restrict__ rowptr, int n) {
    __shared__ int sums[1024];
    int carry = 0;
    if (threadIdx.x == 0) rowptr[0] = 0;
    for (int base = 0; base < n; base += 16384) {
        int start = base + (int)threadIdx.x * 16;
        int vals[16];
        int lsum = 0;
#pragma unroll
        for (int j = 0; j < 16; j++) {
            int idx = start + j;
            vals[j] = (idx < n) ? deg[idx] : 0;
            lsum += vals[j];
        }
        sums[threadIdx.x] = lsum;
        __syncthreads();
        for (int off = 1; off < 1024; off <<= 1) {
            int t = (threadIdx.x >= (unsigned)off) ? sums[threadIdx.x - off] : 0;
            __syncthreads();
            sums[threadIdx.x] += t;
            __syncthreads();
        }
        int excl = (threadIdx.x == 0) ? 0 : sums[threadIdx.x - 1];
        int run = carry + excl;
#pragma unroll
        for (int j = 0; j < 16; j++) {
            int idx = start + j;
            if (idx < n) {
                run += vals[j];
                rowptr[idx + 1] = run;
            }
        }
        carry += sums[1023];
        __syncthreads();
    }
}

__global__ void k_scatter(const int* __restrict__ src, const int* __restrict__ dst, int E,
                          const int* __restrict__ rowptr, int* __restrict__ cursor,
                          int* __restrict__ csr_src) {
    int i = blockIdx.x * blockDim.x + threadIdx.x;
    int stride = gridDim.x * blockDim.x;
    for (; i < E; i += stride) {
        int d = dst[i];
        int slot = rowptr[d] + atomicAdd(&cursor[d], 1);
        csr_src[slot] = src[i];
    }
}

// ---------------- GEMM: Y[n,M] = X[n,K] @ W[K,M] ----------------

template <int K, int M>
__global__ __launch_bounds__(256) void k_gemm(const float* __restrict__ X,
                                              const float* __restrict__ W,
                                              float* __restrict__ Y, int n) {
    constexpr int KH = 64;
    __shared__ float Ws[KH * M];
    __shared__ float Xs[32][K + 4];
    int tid = threadIdx.x;
    int row0 = blockIdx.x * 32;

    for (int idx = tid; idx < 32 * (K / 4); idx += 256) {
        int r = idx / (K / 4), c4 = idx % (K / 4);
        int gr = row0 + r;
        float4 v = make_float4(0.f, 0.f, 0.f, 0.f);
        if (gr < n) v = *reinterpret_cast<const float4*>(&X[(size_t)gr * K + c4 * 4]);
        *reinterpret_cast<float4*>(&Xs[r][c4 * 4]) = v;
    }

    constexpr int NJ = M / 32;
    float4 acc[NJ];
#pragma unroll
    for (int j = 0; j < NJ; j++) acc[j] = make_float4(0.f, 0.f, 0.f, 0.f);
    int r = tid >> 3, cg = tid & 7;

    for (int kh = 0; kh < K; kh += KH) {
        __syncthreads();
        for (int idx = tid; idx < (KH * M) / 4; idx += 256) {
            *reinterpret_cast<float4*>(&Ws[idx * 4]) =
                *reinterpret_cast<const float4*>(&W[(size_t)kh * M + idx * 4]);
        }
        __syncthreads();
        for (int k = 0; k < KH; k++) {
            float xv = Xs[r][kh + k];
#pragma unroll
            for (int j = 0; j < NJ; j++) {
                float4 wv = *reinterpret_cast<const float4*>(&Ws[k * M + cg * 4 + j * 32]);
                acc[j].x += xv * wv.x;
                acc[j].y += xv * wv.y;
                acc[j].z += xv * wv.z;
                acc[j].w += xv * wv.w;
            }
        }
    }

    int gr = row0 + r;
    if (gr < n) {
#pragma unroll
        for (int j = 0; j < NJ; j++)
            *reinterpret_cast<float4*>(&Y[(size_t)gr * M + cg * 4 + j * 32]) = acc[j];
    }
}

// ---------------- attention scalar scores: asrc/adst [n,H] ----------------

template <int H>
__global__ void k_scores(const float* __restrict__ h, const float* __restrict__ a_src,
                         const float* __restrict__ a_dst, float* __restrict__ asrc,
                         float* __restrict__ adst, int n) {
    int wid = blockIdx.x * (blockDim.x >> 6) + (threadIdx.x >> 6);
    int lane = threadIdx.x & 63;
    if (wid >= n) return;
#pragma unroll
    for (int head = 0; head < H; head++) {
        float v = h[(size_t)wid * (H * 64) + head * 64 + lane];
        float s = v * a_src[head * 64 + lane];
        float d = v * a_dst[head * 64 + lane];
#pragma unroll
        for (int m = 1; m < 64; m <<= 1) {
            s += __shfl_xor(s, m, 64);
            d += __shfl_xor(d, m, 64);
        }
        if (lane == 0) {
            asrc[wid * H + head] = s;
            adst[wid * H + head] = d;
        }
    }
}

// ---------------- GAT gather: one wave per (node, head) ----------------
// Single fused pass: aggregation uses unnormalized p (softmax scale applied at
// the end), so no separate denom sweep. 16 lanes per edge-row (float4 loads),
// 4 edges in flight per wave (groups round-robin over edges for balance).
// Max-subtraction skipped: scores are O(1), exp can't overflow; softmax is
// shift-invariant so result matches the reference up to rounding.

template <int H>
__global__ __launch_bounds__(256) void k_gat(const float* __restrict__ h,
                                             const float* __restrict__ asrc,
                                             const float* __restrict__ adst,
                                             const int* __restrict__ rowptr,
                                             const int* __restrict__ csr_src,
                                             const float* __restrict__ bias,
                                             float* __restrict__ out, int n) {
    int wid = blockIdx.x * (blockDim.x >> 6) + (threadIdx.x >> 6);
    int lane = threadIdx.x & 63;
    int node = wid / H, head = wid % H;
    if (node >= n) return;

    int beg = rowptr[node], end = rowptr[node + 1];
    float adst_n = adst[node * H + head];
    float asrc_n = asrc[node * H + head];

    float e0 = asrc_n + adst_n;
    e0 = e0 > 0.f ? e0 : NEG * e0;
    float p_self = __expf(e0);

    int g = lane >> 4;          // edge group 0..3
    int c4 = (lane & 15) << 2;  // channel quad

    float4 acc = make_float4(0.f, 0.f, 0.f, 0.f);
    float psum = 0.f;

    for (int base = beg; base < end; base += 64) {
        int i = base + lane;
        float p = 0.f;
        int s = 0;
        if (i < end) {
            s = csr_src[i];
            float e = asrc[s * H + head] + adst_n;
            e = e > 0.f ? e : NEG * e;
            p = __expf(e);
            psum += p;
        }
        int cnt = min(64, end - base);
        int nt = (cnt + 3) >> 2;
#pragma unroll 4
        for (int t = 0; t < nt; t++) {
            int ej = t * 4 + g;  // this group's edge within the chunk
            float pj = __shfl(p, ej, 64);
            int sj = __shfl(s, ej, 64);
            if (ej < cnt) {
                const float4 hv =
                    *reinterpret_cast<const float4*>(&h[(size_t)sj * (H * 64) + head * 64 + c4]);
                acc.x += pj * hv.x;
                acc.y += pj * hv.y;
                acc.z += pj * hv.z;
                acc.w += pj * hv.w;
            }
        }
    }

    // denom across all lanes
#pragma unroll
    for (int m = 1; m < 64; m <<= 1) psum += __shfl_xor(psum, m, 64);
    float inv = 1.f / (psum + p_self + 1e-16f);

    // combine the 4 edge-groups' partial channel sums
#pragma unroll
    for (int m = 16; m < 64; m <<= 1) {
        acc.x += __shfl_xor(acc.x, m, 64);
        acc.y += __shfl_xor(acc.y, m, 64);
        acc.z += __shfl_xor(acc.z, m, 64);
        acc.w += __shfl_xor(acc.w, m, 64);
    }

    const float4 hself =
        *reinterpret_cast<const float4*>(&h[(size_t)node * (H * 64) + head * 64 + c4]);
    const float4 bv = *reinterpret_cast<const float4*>(&bias[head * 64 + c4]);
    float4 o;
    o.x = fmaxf((acc.x + p_self * hself.x) * inv + bv.x, 0.f);
    o.y = fmaxf((acc.y + p_self * hself.y) * inv + bv.y, 0.f);
    o.z = fmaxf((acc.z + p_self * hself.z) * inv + bv.z, 0.f);
    o.w = fmaxf((acc.w + p_self * hself.w) * inv + bv.w, 0.f);

    if (lane < 16)
        *reinterpret_cast<float4*>(&out[(size_t)node * (H * 64) + head * 64 + c4]) = o;
}

// ---------------- final linear: out[n,16] = h[n,64] @ Wl[64,16] + bl ----------------

__global__ void k_final(const float* __restrict__ h, const float* __restrict__ Wl,
                        const float* __restrict__ bl, float* __restrict__ out, int n) {
    __shared__ float Ws[64 * 16];
    __shared__ float bs[16];
    int tid = threadIdx.x;
    for (int idx = tid; idx < 64 * 16; idx += 256) Ws[idx] = Wl[idx];
    if (tid < 16) bs[tid] = bl[tid];
    __syncthreads();
    int row = blockIdx.x * 16 + (tid >> 4);
    int col = tid & 15;
    if (row >= n) return;
    const float* hr = h + (size_t)row * 64;
    float a = 0.f;
#pragma unroll
    for (int k = 0; k < 64; k++) a += hr[k] * Ws[k * 16 + col];
    out[(size_t)row * 16 + col] = a + bs[col];
}

// ---------------- launch ----------------

extern "C" void kernel_launch(void* const* d_in, const int* in_sizes, int n_in,
                              void* d_out, int out_size, void* d_ws, size_t ws_size,
                              hipStream_t stream) {
    const float* x      = (const float*)d_in[0];
    const int*   ei     = (const int*)d_in[1];
    const float* W1     = (const float*)d_in[2];
    const float* a_src1 = (const float*)d_in[3];
    const float* a_dst1 = (const float*)d_in[4];
    const float* b1     = (const float*)d_in[5];
    const float* W2     = (const float*)d_in[6];
    const float* a_src2 = (const float*)d_in[7];
    const float* a_dst2 = (const float*)d_in[8];
    const float* b2     = (const float*)d_in[9];
    const float* Wl     = (const float*)d_in[10];
    const float* bl     = (const float*)d_in[11];
    float* out = (float*)d_out;

    int n = in_sizes[0] / 128;
    int E = in_sizes[1] / 2;
    const int* src = ei;
    const int* dst = ei + E;

    char* w = (char*)d_ws;
    size_t off = 0;
    auto alloc = [&](size_t bytes) {
        void* p = w + off;
        off = (off + bytes + 255) & ~(size_t)255;
        return p;
    };
    int*   deg    = (int*)alloc((size_t)n * 4);
    int*   cursor = (int*)alloc((size_t)n * 4);
    int*   rowptr = (int*)alloc((size_t)(n + 1) * 4);
    int*   csr    = (int*)alloc((size_t)E * 4);
    float* h1     = (float*)alloc((size_t)n * 128 * 4);
    float* as1    = (float*)alloc((size_t)n * 2 * 4);
    float* ad1    = (float*)alloc((size_t)n * 2 * 4);
    float* hm     = (float*)alloc((size_t)n * 128 * 4);
    float* h2     = (float*)alloc((size_t)n * 64 * 4);
    float* as2    = (float*)alloc((size_t)n * 4);
    float* ad2    = (float*)alloc((size_t)n * 4);
    float* h3     = (float*)alloc((size_t)n * 64 * 4);

    hipMemsetAsync(deg, 0, (size_t)n * 4, stream);
    hipMemsetAsync(cursor, 0, (size_t)n * 4, stream);

    k_count<<<2048, 256, 0, stream>>>(dst, E, deg);
    k_scan<<<1, 1024, 0, stream>>>(deg, rowptr, n);
    k_scatter<<<2048, 256, 0, stream>>>(src, dst, E, rowptr, cursor, csr);

    // layer 1 (heads=2)
    k_gemm<128, 128><<<(n + 31) / 32, 256, 0, stream>>>(x, W1, h1, n);
    k_scores<2><<<(n + 3) / 4, 256, 0, stream>>>(h1, a_src1, a_dst1, as1, ad1, n);
    k_gat<2><<<(2 * n + 3) / 4, 256, 0, stream>>>(h1, as1, ad1, rowptr, csr, b1, hm, n);

    // layer 2 (heads=1)
    k_gemm<128, 64><<<(n + 31) / 32, 256, 0, stream>>>(hm, W2, h2, n);
    k_scores<1><<<(n + 3) / 4, 256, 0, stream>>>(h2, a_src2, a_dst2, as2, ad2, n);
    k_gat<1><<<(n + 3) / 4, 256, 0, stream>>>(h2, as2, ad2, rowptr, csr, b2, h3, n);

    // head
    k_final<<<(n + 15) / 16, 256, 0, stream>>>(h3, Wl, bl, out, n);
}